// Round 12
// baseline (852.332 us; speedup 1.0000x reference)
//
#include <hip/hip_runtime.h>
#include <hip/hip_bf16.h>
#include <hip/hip_fp16.h>

#define N_NODES 50000
#define N_EDGES 1600000
#define E_TOT   1650000   // N_EDGES + N_NODES self loops
#define N_PAIRS 2000000
#define N_GRAPHS 50
#define SCAN_NB 196       // ceil(N_NODES/256)
#define NB2 256           // radix buckets
#define BSZ 196           // nodes per bucket (256*196 = 50176 >= N_NODES)
#define SCAT_BLOCKS 256

typedef __attribute__((ext_vector_type(2))) _Float16 half2_t;
typedef __attribute__((ext_vector_type(4))) _Float16 half4_t;
typedef __attribute__((ext_vector_type(8))) _Float16 half8_t;
typedef __attribute__((ext_vector_type(4))) float floatx4;

union H8 { half8_t v; half2_t h2[4]; uint32_t u[4]; };

// ---------------- time embedding: h0h[:, :128]=x, h0h[:,128:384]=swish(...) (fp16 out)
__global__ void k_time_embed(const float* __restrict__ x, const float* __restrict__ t,
                             const float* __restrict__ tW, const float* __restrict__ tb,
                             _Float16* __restrict__ h0h) {
    int i = blockIdx.x;
    int tid = threadIdx.x;
    float ta = t[i];                       // T_LIMIT = 1.0
    float s = sinf(ta * 1.5707963267948966f);
    float c = cosf(ta * 1.5707963267948966f);
    if (tid < 128) h0h[(size_t)i*384 + tid] = (_Float16)x[(size_t)i*128 + tid];
    float v = s*tW[tid] + c*tW[256+tid] + ta*tW[512+tid] + tb[tid];
    float sw = v / (1.f + __expf(-v));
    h0h[(size_t)i*384 + 128 + tid] = (_Float16)sw;
}

// ---------------- weight convert: WT[n][k] = (n<128?Wl:Wr)[k][n&127] as fp16; b2 combined
__global__ void k_cvt_w(const float* __restrict__ Wl, const float* __restrict__ Wr,
                        const float* __restrict__ bl, const float* __restrict__ br,
                        int K, _Float16* __restrict__ WT, float* __restrict__ b2) {
    int idx = blockIdx.x*256 + threadIdx.x;
    if (idx < 256) b2[idx] = (idx < 128) ? bl[idx] : br[idx-128];
    if (idx >= 256*K) return;
    int n = idx / K, k = idx - n*K;
    float v = (n < 128) ? Wl[k*128 + n] : Wr[k*128 + (n-128)];
    WT[idx] = (_Float16)v;
}

// batch is sorted: derive graph offsets without atomics
__global__ void k_goff(const int* __restrict__ batch, int* __restrict__ goff) {
    int i = blockIdx.x*256 + threadIdx.x;
    if (i >= N_NODES) return;
    int bi = batch[i];
    if (i == 0) {
        for (int g = 0; g <= bi; ++g) goff[g] = 0;
    } else {
        int bp = batch[i-1];
        for (int g = bp+1; g <= bi; ++g) goff[g] = i;
    }
    if (i == N_NODES-1) {
        for (int g = bi+1; g <= N_GRAPHS; ++g) goff[g] = N_NODES;
    }
}

// ---------------- CSR build: radix partition into 256 buckets of 196 nodes ---
// Bucket histogram (LDS-aggregated -> 256 global adds per block)
__global__ __launch_bounds__(256) void k_bhist(const int* __restrict__ ei,
                                               int* __restrict__ bcnt) {
    __shared__ int lh[NB2];
    int tid = threadIdx.x;
    lh[tid] = 0;
    __syncthreads();
    int chunk = (E_TOT + gridDim.x - 1) / gridDim.x;
    int e0 = blockIdx.x * chunk;
    int e1 = min(e0 + chunk, E_TOT);
    for (int e = e0 + tid; e < e1; e += 256) {
        int dst = (e < N_EDGES) ? ei[N_EDGES + e] : (e - N_EDGES);
        atomicAdd(&lh[dst / BSZ], 1);
    }
    __syncthreads();
    if (lh[tid]) atomicAdd(&bcnt[tid], lh[tid]);
}

// Exclusive scan of 256 bucket counts -> bucket bases + cursors
__global__ void k_bscan(const int* __restrict__ bcnt, int* __restrict__ bbase,
                        int* __restrict__ bcursor) {
    __shared__ int tmp[NB2];
    int tid = threadIdx.x;
    int v = bcnt[tid];
    tmp[tid] = v; __syncthreads();
    for (int off = 1; off < NB2; off <<= 1) {
        int t = (tid >= off) ? tmp[tid-off] : 0;
        __syncthreads();
        tmp[tid] += t;
        __syncthreads();
    }
    int excl = tmp[tid] - v;
    bbase[tid] = excl;
    bcursor[tid] = excl;
    if (tid == NB2-1) bbase[NB2] = tmp[tid];   // == E_TOT
}

// Pass 1: each block reserves ONE contiguous run per bucket (single global
// atomic per (block,bucket)) and writes its edges contiguously into that run
// -> same-block, line-local stores.
// Packed: (dst % BSZ) << 16 | src   (src < 65536, dstLocal < 256)
__global__ __launch_bounds__(256) void k_scat1(const int* __restrict__ ei,
                                               int* __restrict__ bcursor,
                                               unsigned int* __restrict__ stage) {
    __shared__ int lh[NB2];
    __shared__ int lpos[NB2];
    int tid = threadIdx.x;
    lh[tid] = 0;
    __syncthreads();
    int chunk = (E_TOT + gridDim.x - 1) / gridDim.x;
    int e0 = blockIdx.x * chunk;
    int e1 = min(e0 + chunk, E_TOT);
    for (int e = e0 + tid; e < e1; e += 256) {
        int dst = (e < N_EDGES) ? ei[N_EDGES + e] : (e - N_EDGES);
        atomicAdd(&lh[dst / BSZ], 1);
    }
    __syncthreads();
    int cnt = lh[tid];
    lpos[tid] = cnt ? atomicAdd(&bcursor[tid], cnt) : 0;
    __syncthreads();
    for (int e = e0 + tid; e < e1; e += 256) {
        int src, dst;
        if (e < N_EDGES) { src = ei[e]; dst = ei[N_EDGES + e]; }
        else             { src = e - N_EDGES; dst = src; }
        int b = dst / BSZ;
        int dl = dst - b * BSZ;
        int pos = atomicAdd(&lpos[b], 1);
        stage[pos] = ((unsigned int)dl << 16) | (unsigned int)src;
    }
}

// Pass 2: one block per bucket. Local per-node histogram + LDS scan produces
// row_ptr for the bucket's nodes; scatter confined to the bucket's ~26KB
// L2-resident CSR window.
__global__ __launch_bounds__(256) void k_scat2(
    const unsigned int* __restrict__ stage, const int* __restrict__ bbase,
    int* __restrict__ row_ptr, int* __restrict__ csr_src) {
    __shared__ int hist[NB2];
    __shared__ int cur[NB2];
    int b = blockIdx.x;
    int tid = threadIdx.x;
    hist[tid] = 0;
    __syncthreads();
    int p0 = bbase[b], p1 = bbase[b+1];
    for (int p = p0 + tid; p < p1; p += 256)
        atomicAdd(&hist[stage[p] >> 16], 1);
    __syncthreads();
    int v = hist[tid];
    cur[tid] = v; __syncthreads();
    for (int off = 1; off < NB2; off <<= 1) {
        int t = (tid >= off) ? cur[tid-off] : 0;
        __syncthreads();
        cur[tid] += t;
        __syncthreads();
    }
    int excl = cur[tid] - v;
    int node = b*BSZ + tid;
    if (tid < BSZ && node < N_NODES) row_ptr[node] = p0 + excl;
    __syncthreads();
    cur[tid] = p0 + excl;
    __syncthreads();
    for (int p = p0 + tid; p < p1; p += 256) {
        unsigned int u = stage[p];
        int dl = (int)(u >> 16);
        int pos = atomicAdd(&cur[dl], 1);
        csr_src[pos] = (int)(u & 0xFFFFu);
    }
    if (b == NB2-1 && tid == 0) row_ptr[N_NODES] = E_TOT;
}

// ---------------- dual GEMM via MFMA (fp16 A input, layer 0) ----------------
template<int K>
__global__ __launch_bounds__(256) void k_gemm_mfma(
    const _Float16* __restrict__ Ah, const _Float16* __restrict__ WT,
    const float* __restrict__ b2,
    _Float16* __restrict__ xl_h, float* __restrict__ xr) {
    int wave = (blockIdx.x*256 + threadIdx.x) >> 6;
    int lane = threadIdx.x & 63;
    if (wave >= N_NODES/16) return;
    int m0 = wave * 16;
    int r16 = lane & 15, quad = lane >> 4;
    constexpr int KT = K / 32;
    half8_t afrag[KT];
    const _Float16* arow = Ah + (size_t)(m0 + r16)*K + quad*8;
    #pragma unroll
    for (int kt = 0; kt < KT; ++kt)
        afrag[kt] = *(const half8_t*)(arow + kt*32);
    #pragma unroll
    for (int nt = 0; nt < 16; ++nt) {
        floatx4 acc = {0.f, 0.f, 0.f, 0.f};
        const _Float16* brow = WT + (size_t)(nt*16 + r16)*K + quad*8;
        #pragma unroll
        for (int kt = 0; kt < KT; ++kt) {
            half8_t bfrag = *(const half8_t*)(brow + kt*32);
            acc = __builtin_amdgcn_mfma_f32_16x16x32_f16(afrag[kt], bfrag, acc, 0, 0, 0);
        }
        int col = nt*16 + r16;
        float bv = b2[col];
        if (nt < 8) {
            #pragma unroll
            for (int r = 0; r < 4; ++r)
                xl_h[(size_t)(m0 + quad*4 + r)*128 + col] = (_Float16)(acc[r] + bv);
        } else {
            #pragma unroll
            for (int r = 0; r < 4; ++r)
                xr[(size_t)(m0 + quad*4 + r)*128 + (col-128)] = acc[r] + bv;
        }
    }
}

// ---------------- dual GEMM via MFMA with FUSED graph-LN on the input
// (layers 1..3): A = LN(hout) applied while packing fragments. K=128.
__global__ __launch_bounds__(256) void k_gemm_ln_mfma(
    const float* __restrict__ hout, const int* __restrict__ batch,
    const int* __restrict__ goff, const float* __restrict__ gsum,
    const float* __restrict__ gsumsq, const float* __restrict__ lnw,
    const float* __restrict__ lnb, const _Float16* __restrict__ WT,
    const float* __restrict__ b2,
    _Float16* __restrict__ xl_h, float* __restrict__ xr) {
    int wave = (blockIdx.x*256 + threadIdx.x) >> 6;
    int lane = threadIdx.x & 63;
    if (wave >= N_NODES/16) return;
    int m0 = wave * 16;
    int r16 = lane & 15, quad = lane >> 4;
    int row = m0 + r16;
    int g = batch[row];
    float cnt = (float)(goff[g+1] - goff[g]) * 128.f;
    cnt = fmaxf(cnt, 1.f);
    float mean = gsum[g] / cnt;
    float var = gsumsq[g] / cnt - mean*mean;
    var = fmaxf(var, 0.f);
    float rstd = rsqrtf(var + 1e-5f);

    half8_t afrag[4];
    const float* arow = hout + (size_t)row*128 + quad*8;
    #pragma unroll
    for (int kt = 0; kt < 4; ++kt) {
        int c = quad*8 + kt*32;
        const float4* v4 = (const float4*)(arow + kt*32);
        const float4* w4 = (const float4*)(lnw + c);
        const float4* b4 = (const float4*)(lnb + c);
        float4 v0 = v4[0], v1 = v4[1];
        float4 w0 = w4[0], w1 = w4[1];
        float4 bb0 = b4[0], bb1 = b4[1];
        float vv[8] = {v0.x,v0.y,v0.z,v0.w,v1.x,v1.y,v1.z,v1.w};
        float ww[8] = {w0.x,w0.y,w0.z,w0.w,w1.x,w1.y,w1.z,w1.w};
        float bz[8] = {bb0.x,bb0.y,bb0.z,bb0.w,bb1.x,bb1.y,bb1.z,bb1.w};
        #pragma unroll
        for (int j = 0; j < 8; ++j)
            afrag[kt][j] = (_Float16)((vv[j] - mean) * rstd * ww[j] + bz[j]);
    }
    #pragma unroll
    for (int nt = 0; nt < 16; ++nt) {
        floatx4 acc = {0.f, 0.f, 0.f, 0.f};
        const _Float16* brow = WT + (size_t)(nt*16 + r16)*128 + quad*8;
        #pragma unroll
        for (int kt = 0; kt < 4; ++kt) {
            half8_t bfrag = *(const half8_t*)(brow + kt*32);
            acc = __builtin_amdgcn_mfma_f32_16x16x32_f16(afrag[kt], bfrag, acc, 0, 0, 0);
        }
        int col = nt*16 + r16;
        float bv = b2[col];
        if (nt < 8) {
            #pragma unroll
            for (int r = 0; r < 4; ++r)
                xl_h[(size_t)(m0 + quad*4 + r)*128 + col] = (_Float16)(acc[r] + bv);
        } else {
            #pragma unroll
            for (int r = 0; r < 4; ++r)
                xr[(size_t)(m0 + quad*4 + r)*128 + (col-128)] = acc[r] + bv;
        }
    }
}

// ---------------- GATv2 aggregation: one wave per node.
// 16 lanes per edge (8 ch/lane, one 16B half8 gather), 4 edge slots/wave,
// edge loop unrolled x2 -> 16 edges & 4 independent 1KB gathers in flight
// (kernel runs at ~2.3 TB/s of a ~3.4 TB/s miss-path ceiling: MLP-limited).
// Max-free softmax; packed-fp16 logit math (pk_add + and-mask + fdot2).
__global__ __launch_bounds__(256) void k_gat(
    const _Float16* __restrict__ xl_h, const float* __restrict__ xr,
    const int* __restrict__ row_ptr, const int* __restrict__ csr_src,
    const float* __restrict__ att, const float* __restrict__ bias,
    float* __restrict__ hout, float2* __restrict__ nstats) {
    int wave = (blockIdx.x * 256 + threadIdx.x) >> 6;
    int lane = threadIdx.x & 63;
    if (wave >= N_NODES) return;
    int i = wave;
    int slot = lane >> 4;        // edge slot 0..3
    int l16  = lane & 15;        // lane within edge group
    int c0   = l16 * 8;          // 8 contiguous channels per lane

    H8 atth, xrh;
    {
        const float4* a4 = (const float4*)(att + c0);
        const float4* r4 = (const float4*)(xr + (size_t)i*128 + c0);
        float4 a0 = a4[0], a1 = a4[1], r0 = r4[0], r1 = r4[1];
        float af[8] = {a0.x,a0.y,a0.z,a0.w,a1.x,a1.y,a1.z,a1.w};
        float rf[8] = {r0.x,r0.y,r0.z,r0.w,r1.x,r1.y,r1.z,r1.w};
        #pragma unroll
        for (int j = 0; j < 8; ++j) {
            atth.v[j] = (_Float16)af[j];
            xrh.v[j]  = (_Float16)rf[j];
        }
    }
    int p0 = row_ptr[i], p1 = row_ptr[i+1];

    float denom = 0.f;
    float acc[8];
    #pragma unroll
    for (int j = 0; j < 8; ++j) acc[j] = 0.f;

    for (int p = p0; p < p1; p += 16) {
        int idx[4];
        #pragma unroll
        for (int j = 0; j < 4; ++j) {
            int e = p + j*4 + slot;
            idx[j] = csr_src[(e < p1) ? e : (p1 - 1)];
        }
        H8 g[4];
        #pragma unroll
        for (int j = 0; j < 4; ++j)
            g[j].v = *(const half8_t*)(xl_h + (size_t)idx[j]*128 + c0);
        float pt[4];
        #pragma unroll
        for (int j = 0; j < 4; ++j) {
            H8 m;
            m.v = g[j].v + xrh.v;
            float pa = 0.f, pb = 0.f;
            #pragma unroll
            for (int k = 0; k < 4; ++k) {
                half2_t ab = __builtin_bit_cast(half2_t, m.u[k] & 0x7FFF7FFFu);
                pa = __builtin_amdgcn_fdot2(m.h2[k], atth.h2[k], pa, false);
                pb = __builtin_amdgcn_fdot2(ab,      atth.h2[k], pb, false);
            }
            pt[j] = 0.6f*pa + 0.4f*pb;
        }
        #pragma unroll
        for (int j = 0; j < 4; ++j) {
            pt[j] += __shfl_xor(pt[j], 1);
            pt[j] += __shfl_xor(pt[j], 2);
        }
        float w[4];
        #pragma unroll
        for (int j = 0; j < 4; ++j)
            w[j] = (p + j*4 + slot < p1) ? __expf(pt[j]) : 0.f;
        denom += (w[0] + w[1]) + (w[2] + w[3]);
        #pragma unroll
        for (int j = 0; j < 4; ++j) {
            #pragma unroll
            for (int k = 0; k < 8; ++k)
                acc[k] = fmaf(w[j], (float)g[j].v[k], acc[k]);
        }
    }
    // merge the 4 edge-slot chains (lanes differing in bits 4,5)
    #pragma unroll
    for (int off = 16; off <= 32; off <<= 1) {
        denom += __shfl_xor(denom, off);
        #pragma unroll
        for (int j = 0; j < 8; ++j) acc[j] += __shfl_xor(acc[j], off);
    }
    float inv = 1.f / (denom + 1e-16f);
    float v[8];
    float s1 = 0.f, s2 = 0.f;
    #pragma unroll
    for (int j = 0; j < 8; ++j) {
        v[j] = acc[j] * inv + bias[c0 + j];
        s1 += v[j];
        s2 = fmaf(v[j], v[j], s2);
    }
    if (slot == 0) {
        float4* o4 = (float4*)(hout + (size_t)i*128 + c0);
        o4[0] = make_float4(v[0], v[1], v[2], v[3]);
        o4[1] = make_float4(v[4], v[5], v[6], v[7]);
    }
    #pragma unroll
    for (int off = 1; off < 16; off <<= 1) {
        s1 += __shfl_xor(s1, off);
        s2 += __shfl_xor(s2, off);
    }
    if (lane == 0) nstats[i] = make_float2(s1, s2);
}

// ---------------- per-graph reduction of node stats (plain stores) ----------
__global__ __launch_bounds__(256) void k_graph_red(
    const float2* __restrict__ nstats, const int* __restrict__ goff,
    float* __restrict__ gsum, float* __restrict__ gsumsq) {
    __shared__ float l1[256], l2[256];
    int g = blockIdx.x;
    int tid = threadIdx.x;
    int a = goff[g], b = goff[g+1];
    float s1 = 0.f, s2 = 0.f;
    for (int i = a + tid; i < b; i += 256) {
        float2 v = nstats[i];
        s1 += v.x; s2 += v.y;
    }
    l1[tid] = s1; l2[tid] = s2; __syncthreads();
    for (int off = 128; off > 0; off >>= 1) {
        if (tid < off) { l1[tid] += l1[tid+off]; l2[tid] += l2[tid+off]; }
        __syncthreads();
    }
    if (tid == 0) { gsum[g] = l1[0]; gsumsq[g] = l2[0]; }
}

// ---------------- final graph layernorm (fp16 out, feeds k_pairs only) -------
__global__ void k_ln(const float* __restrict__ hout, const int* __restrict__ batch,
                     const int* __restrict__ goff, const float* __restrict__ gsum,
                     const float* __restrict__ gsumsq, const float* __restrict__ w,
                     const float* __restrict__ b, _Float16* __restrict__ hb) {
    int idx = blockIdx.x*256 + threadIdx.x;
    if (idx >= N_NODES*128) return;
    int i = idx >> 7, c = idx & 127;
    int g = batch[i];
    float cnt = (float)(goff[g+1] - goff[g]) * 128.f;
    cnt = fmaxf(cnt, 1.f);
    float mean = gsum[g] / cnt;
    float var = gsumsq[g] / cnt - mean*mean;
    var = fmaxf(var, 0.f);
    float rstd = rsqrtf(var + 1e-5f);
    float v = (hout[idx] - mean) * rstd * w[c] + b[c];
    hb[idx] = (_Float16)v;
}

// ---------------- pair scoring: 16 lanes/pair, SINGLE gathered array,
// link_W folded into per-lane fp16 registers ----------
__global__ __launch_bounds__(256) void k_pairs(
    const _Float16* __restrict__ hb, const int* __restrict__ pi,
    const float* __restrict__ lW, const float* __restrict__ lb,
    float* __restrict__ out) {
    int grp = (blockIdx.x*256 + threadIdx.x) >> 4;
    int q = threadIdx.x & 15;
    if (grp >= N_PAIRS) return;
    H8 w;
    #pragma unroll
    for (int j = 0; j < 8; ++j) w.v[j] = (_Float16)lW[q*8 + j];
    int p0 = pi[grp], p1 = pi[N_PAIRS + grp];
    const half8_t* B = (const half8_t*)hb;
    H8 a, b, prod;
    a.v = B[(size_t)p0*16 + q];
    b.v = B[(size_t)p1*16 + q];
    prod.v = a.v * b.v;
    float part = 0.f;
    #pragma unroll
    for (int j = 0; j < 4; ++j)
        part = __builtin_amdgcn_fdot2(prod.h2[j], w.h2[j], part, false);
    part += __shfl_xor(part, 1);
    part += __shfl_xor(part, 2);
    part += __shfl_xor(part, 4);
    part += __shfl_xor(part, 8);
    if (q == 0) out[grp] = 1.f / (1.f + __expf(-(part + lb[0])));
}

extern "C" void kernel_launch(void* const* d_in, const int* in_sizes, int n_in,
                              void* d_out, int out_size, void* d_ws, size_t ws_size,
                              hipStream_t stream) {
    const float* x     = (const float*)d_in[0];
    const float* t     = (const float*)d_in[1];
    const int*   ei    = (const int*)  d_in[2];
    const int*   pi    = (const int*)  d_in[3];
    const int*   batch = (const int*)  d_in[4];
    const float* tW    = (const float*)d_in[5];
    const float* tb    = (const float*)d_in[6];
    const float* W0l   = (const float*)d_in[7];
    const float* b0l   = (const float*)d_in[8];
    const float* W0r   = (const float*)d_in[9];
    const float* b0r   = (const float*)d_in[10];
    const float* att0  = (const float*)d_in[11];
    const float* bias0 = (const float*)d_in[12];
    const float* Wl    = (const float*)d_in[13];
    const float* bl    = (const float*)d_in[14];
    const float* Wr    = (const float*)d_in[15];
    const float* br    = (const float*)d_in[16];
    const float* att   = (const float*)d_in[17];
    const float* bias  = (const float*)d_in[18];
    const float* lnw   = (const float*)d_in[19];
    const float* lnb   = (const float*)d_in[20];
    const float* lW    = (const float*)d_in[21];
    const float* lb    = (const float*)d_in[22];
    float* out = (float*)d_out;

    char* ws = (char*)d_ws;
    size_t off = 0;
    auto walloc = [&](size_t bytes) -> void* {
        void* p = ws + off;
        off += (bytes + 255) & ~(size_t)255;
        return p;
    };
    _Float16*  h0h     = (_Float16*) walloc((size_t)N_NODES*384*2);
    float*     hout    = (float*)    walloc((size_t)N_NODES*128*4);
    _Float16*  xl_h    = (_Float16*) walloc((size_t)N_NODES*128*2);
    float*     xr      = (float*)    walloc((size_t)N_NODES*128*4);
    _Float16*  hb      = (_Float16*) walloc((size_t)N_NODES*128*2);
    int*       row_ptr = (int*)      walloc((size_t)(N_NODES+1)*4);
    int*       csr_src = (int*)      walloc((size_t)E_TOT*4);
    unsigned int* stage = (unsigned int*)walloc((size_t)E_TOT*4);
    int*       bcnt    = (int*)      walloc(NB2*4);
    int*       bbase   = (int*)      walloc((NB2+1)*4);
    int*       bcursor = (int*)      walloc(NB2*4);
    int*       goff    = (int*)      walloc(64*4);
    float2*    nstats  = (float2*)   walloc((size_t)N_NODES*8);
    float*     stats   = (float*)    walloc(2*64*4);              // [sum|sumsq][64]
    _Float16*  WT0     = (_Float16*) walloc(256*384*2);
    _Float16*  WT123   = (_Float16*) walloc(3*256*128*2);
    float*     b2      = (float*)    walloc(4*256*4);

    hipMemsetAsync(bcnt, 0, NB2*4, stream);

    k_time_embed<<<N_NODES, 256, 0, stream>>>(x, t, tW, tb, h0h);
    k_cvt_w<<<(256*384+255)/256, 256, 0, stream>>>(W0l, W0r, b0l, b0r, 384, WT0, b2);
    for (int l = 0; l < 3; ++l)
        k_cvt_w<<<(256*128+255)/256, 256, 0, stream>>>(
            Wl + (size_t)l*128*128, Wr + (size_t)l*128*128,
            bl + l*128, br + l*128, 128, WT123 + (size_t)l*256*128, b2 + (l+1)*256);
    k_goff<<<SCAN_NB, 256, 0, stream>>>(batch, goff);
    k_bhist<<<SCAT_BLOCKS, 256, 0, stream>>>(ei, bcnt);
    k_bscan<<<1, 256, 0, stream>>>(bcnt, bbase, bcursor);
    k_scat1<<<SCAT_BLOCKS, 256, 0, stream>>>(ei, bcursor, stage);
    k_scat2<<<NB2, 256, 0, stream>>>(stage, bbase, row_ptr, csr_src);

    float* gsum   = stats;
    float* gsumsq = stats + 64;
    const int GEMM_BLOCKS = (N_NODES/16 + 3) / 4;   // 4 waves/block, 16 rows/wave
    for (int L = 0; L < 4; ++L) {
        if (L == 0)
            k_gemm_mfma<384><<<GEMM_BLOCKS, 256, 0, stream>>>(h0h, WT0, b2, xl_h, xr);
        else
            k_gemm_ln_mfma<<<GEMM_BLOCKS, 256, 0, stream>>>(
                hout, batch, goff, gsum, gsumsq, lnw + (L-1)*128, lnb + (L-1)*128,
                WT123 + (size_t)(L-1)*256*128, b2 + L*256, xl_h, xr);
        const float* attL  = (L == 0) ? att0  : att  + (size_t)(L-1)*128;
        const float* biasL = (L == 0) ? bias0 : bias + (size_t)(L-1)*128;
        k_gat<<<N_NODES/4, 256, 0, stream>>>(xl_h, xr, row_ptr, csr_src, attL, biasL,
                                             hout, nstats);
        k_graph_red<<<N_GRAPHS, 256, 0, stream>>>(nstats, goff, gsum, gsumsq);
    }
    k_ln<<<(N_NODES*128+255)/256, 256, 0, stream>>>(hout, batch, goff, gsum, gsumsq,
                                                    lnw + 3*128, lnb + 3*128, hb);
    k_pairs<<<((size_t)N_PAIRS*16 + 255)/256, 256, 0, stream>>>(hb, pi, lW, lb, out);
}

// Round 13
// 811.399 us; speedup vs baseline: 1.0504x; 1.0504x over previous
//
#include <hip/hip_runtime.h>
#include <hip/hip_bf16.h>
#include <hip/hip_fp16.h>

#define N_NODES 50000
#define N_EDGES 1600000
#define E_TOT   1650000   // N_EDGES + N_NODES self loops
#define N_PAIRS 2000000
#define N_GRAPHS 50
#define SCAN_NB 196       // ceil(N_NODES/256)
#define NB2 256           // radix buckets
#define BSZ 196           // nodes per bucket (256*196 = 50176 >= N_NODES)
#define SCAT_BLOCKS 256

typedef __attribute__((ext_vector_type(2))) _Float16 half2_t;
typedef __attribute__((ext_vector_type(4))) _Float16 half4_t;
typedef __attribute__((ext_vector_type(8))) _Float16 half8_t;
typedef __attribute__((ext_vector_type(4))) float floatx4;

union H8 { half8_t v; half2_t h2[4]; uint32_t u[4]; };

// ---------------- time embedding: h0h[:, :128]=x, h0h[:,128:384]=swish(...) (fp16 out)
__global__ void k_time_embed(const float* __restrict__ x, const float* __restrict__ t,
                             const float* __restrict__ tW, const float* __restrict__ tb,
                             _Float16* __restrict__ h0h) {
    int i = blockIdx.x;
    int tid = threadIdx.x;
    float ta = t[i];                       // T_LIMIT = 1.0
    float s = sinf(ta * 1.5707963267948966f);
    float c = cosf(ta * 1.5707963267948966f);
    if (tid < 128) h0h[(size_t)i*384 + tid] = (_Float16)x[(size_t)i*128 + tid];
    float v = s*tW[tid] + c*tW[256+tid] + ta*tW[512+tid] + tb[tid];
    float sw = v / (1.f + __expf(-v));
    h0h[(size_t)i*384 + 128 + tid] = (_Float16)sw;
}

// ---------------- fused weight convert for all 4 layers ----------------
// WT0[n][k] (K=384), WT123[l][n][k] (K=128); b2[L][256] = [bl|br]
__global__ void k_cvt_all(const float* __restrict__ W0l, const float* __restrict__ W0r,
                          const float* __restrict__ b0l, const float* __restrict__ b0r,
                          const float* __restrict__ Wl,  const float* __restrict__ Wr,
                          const float* __restrict__ bl,  const float* __restrict__ br,
                          _Float16* __restrict__ WT0, _Float16* __restrict__ WT123,
                          float* __restrict__ b2) {
    int idx = blockIdx.x*256 + threadIdx.x;
    if (idx < 1024) {
        int L = idx >> 8, c = idx & 255;
        const float* bls = (L == 0) ? b0l : bl + (L-1)*128;
        const float* brs = (L == 0) ? b0r : br + (L-1)*128;
        b2[idx] = (c < 128) ? bls[c] : brs[c-128];
    }
    if (idx < 256*384) {
        int n = idx / 384, k = idx - n*384;
        float v = (n < 128) ? W0l[k*128 + n] : W0r[k*128 + (n-128)];
        WT0[idx] = (_Float16)v;
    } else if (idx < 256*384 + 3*256*128) {
        int r = idx - 256*384;
        int l = r / 32768; int q = r - l*32768;
        int n = q / 128, k = q - n*128;
        float v = (n < 128) ? Wl[(size_t)l*16384 + k*128 + n]
                            : Wr[(size_t)l*16384 + k*128 + (n-128)];
        WT123[r] = (_Float16)v;
    }
}

// batch is sorted: derive graph offsets without atomics
__global__ void k_goff(const int* __restrict__ batch, int* __restrict__ goff) {
    int i = blockIdx.x*256 + threadIdx.x;
    if (i >= N_NODES) return;
    int bi = batch[i];
    if (i == 0) {
        for (int g = 0; g <= bi; ++g) goff[g] = 0;
    } else {
        int bp = batch[i-1];
        for (int g = bp+1; g <= bi; ++g) goff[g] = i;
    }
    if (i == N_NODES-1) {
        for (int g = bi+1; g <= N_GRAPHS; ++g) goff[g] = N_NODES;
    }
}

// ---------------- CSR build: radix partition into 256 buckets of 196 nodes ---
__global__ __launch_bounds__(256) void k_bhist(const int* __restrict__ ei,
                                               int* __restrict__ bcnt) {
    __shared__ int lh[NB2];
    int tid = threadIdx.x;
    lh[tid] = 0;
    __syncthreads();
    int chunk = (E_TOT + gridDim.x - 1) / gridDim.x;
    int e0 = blockIdx.x * chunk;
    int e1 = min(e0 + chunk, E_TOT);
    for (int e = e0 + tid; e < e1; e += 256) {
        int dst = (e < N_EDGES) ? ei[N_EDGES + e] : (e - N_EDGES);
        atomicAdd(&lh[dst / BSZ], 1);
    }
    __syncthreads();
    if (lh[tid]) atomicAdd(&bcnt[tid], lh[tid]);
}

__global__ void k_bscan(const int* __restrict__ bcnt, int* __restrict__ bbase,
                        int* __restrict__ bcursor) {
    __shared__ int tmp[NB2];
    int tid = threadIdx.x;
    int v = bcnt[tid];
    tmp[tid] = v; __syncthreads();
    for (int off = 1; off < NB2; off <<= 1) {
        int t = (tid >= off) ? tmp[tid-off] : 0;
        __syncthreads();
        tmp[tid] += t;
        __syncthreads();
    }
    int excl = tmp[tid] - v;
    bbase[tid] = excl;
    bcursor[tid] = excl;
    if (tid == NB2-1) bbase[NB2] = tmp[tid];   // == E_TOT
}

// Pass 1: block-owned contiguous runs per bucket -> line-local stores.
__global__ __launch_bounds__(256) void k_scat1(const int* __restrict__ ei,
                                               int* __restrict__ bcursor,
                                               unsigned int* __restrict__ stage) {
    __shared__ int lh[NB2];
    __shared__ int lpos[NB2];
    int tid = threadIdx.x;
    lh[tid] = 0;
    __syncthreads();
    int chunk = (E_TOT + gridDim.x - 1) / gridDim.x;
    int e0 = blockIdx.x * chunk;
    int e1 = min(e0 + chunk, E_TOT);
    for (int e = e0 + tid; e < e1; e += 256) {
        int dst = (e < N_EDGES) ? ei[N_EDGES + e] : (e - N_EDGES);
        atomicAdd(&lh[dst / BSZ], 1);
    }
    __syncthreads();
    int cnt = lh[tid];
    lpos[tid] = cnt ? atomicAdd(&bcursor[tid], cnt) : 0;
    __syncthreads();
    for (int e = e0 + tid; e < e1; e += 256) {
        int src, dst;
        if (e < N_EDGES) { src = ei[e]; dst = ei[N_EDGES + e]; }
        else             { src = e - N_EDGES; dst = src; }
        int b = dst / BSZ;
        int dl = dst - b * BSZ;
        int pos = atomicAdd(&lpos[b], 1);
        stage[pos] = ((unsigned int)dl << 16) | (unsigned int)src;
    }
}

// Pass 2: one block per bucket; LDS per-node histogram + scan -> row_ptr;
// scatter confined to the bucket's L2-resident CSR window.
__global__ __launch_bounds__(256) void k_scat2(
    const unsigned int* __restrict__ stage, const int* __restrict__ bbase,
    int* __restrict__ row_ptr, int* __restrict__ csr_src) {
    __shared__ int hist[NB2];
    __shared__ int cur[NB2];
    int b = blockIdx.x;
    int tid = threadIdx.x;
    hist[tid] = 0;
    __syncthreads();
    int p0 = bbase[b], p1 = bbase[b+1];
    for (int p = p0 + tid; p < p1; p += 256)
        atomicAdd(&hist[stage[p] >> 16], 1);
    __syncthreads();
    int v = hist[tid];
    cur[tid] = v; __syncthreads();
    for (int off = 1; off < NB2; off <<= 1) {
        int t = (tid >= off) ? cur[tid-off] : 0;
        __syncthreads();
        cur[tid] += t;
        __syncthreads();
    }
    int excl = cur[tid] - v;
    int node = b*BSZ + tid;
    if (tid < BSZ && node < N_NODES) row_ptr[node] = p0 + excl;
    __syncthreads();
    cur[tid] = p0 + excl;
    __syncthreads();
    for (int p = p0 + tid; p < p1; p += 256) {
        unsigned int u = stage[p];
        int dl = (int)(u >> 16);
        int pos = atomicAdd(&cur[dl], 1);
        csr_src[pos] = (int)(u & 0xFFFFu);
    }
    if (b == NB2-1 && tid == 0) row_ptr[N_NODES] = E_TOT;
}

// ---------------- dual GEMM via MFMA (fp16 A input, layer 0); xr fp16 out ----
template<int K>
__global__ __launch_bounds__(256) void k_gemm_mfma(
    const _Float16* __restrict__ Ah, const _Float16* __restrict__ WT,
    const float* __restrict__ b2,
    _Float16* __restrict__ xl_h, _Float16* __restrict__ xr_h) {
    int wave = (blockIdx.x*256 + threadIdx.x) >> 6;
    int lane = threadIdx.x & 63;
    if (wave >= N_NODES/16) return;
    int m0 = wave * 16;
    int r16 = lane & 15, quad = lane >> 4;
    constexpr int KT = K / 32;
    half8_t afrag[KT];
    const _Float16* arow = Ah + (size_t)(m0 + r16)*K + quad*8;
    #pragma unroll
    for (int kt = 0; kt < KT; ++kt)
        afrag[kt] = *(const half8_t*)(arow + kt*32);
    #pragma unroll
    for (int nt = 0; nt < 16; ++nt) {
        floatx4 acc = {0.f, 0.f, 0.f, 0.f};
        const _Float16* brow = WT + (size_t)(nt*16 + r16)*K + quad*8;
        #pragma unroll
        for (int kt = 0; kt < KT; ++kt) {
            half8_t bfrag = *(const half8_t*)(brow + kt*32);
            acc = __builtin_amdgcn_mfma_f32_16x16x32_f16(afrag[kt], bfrag, acc, 0, 0, 0);
        }
        int col = nt*16 + r16;
        float bv = b2[col];
        if (nt < 8) {
            #pragma unroll
            for (int r = 0; r < 4; ++r)
                xl_h[(size_t)(m0 + quad*4 + r)*128 + col] = (_Float16)(acc[r] + bv);
        } else {
            #pragma unroll
            for (int r = 0; r < 4; ++r)
                xr_h[(size_t)(m0 + quad*4 + r)*128 + (col-128)] = (_Float16)(acc[r] + bv);
        }
    }
}

// ---------------- dual GEMM via MFMA with FUSED graph-LN on the input
// (layers 1..3): A = LN(hout) applied while packing fragments. K=128.
__global__ __launch_bounds__(256) void k_gemm_ln_mfma(
    const float* __restrict__ hout, const int* __restrict__ batch,
    const int* __restrict__ goff, const float* __restrict__ gsum,
    const float* __restrict__ gsumsq, const float* __restrict__ lnw,
    const float* __restrict__ lnb, const _Float16* __restrict__ WT,
    const float* __restrict__ b2,
    _Float16* __restrict__ xl_h, _Float16* __restrict__ xr_h) {
    int wave = (blockIdx.x*256 + threadIdx.x) >> 6;
    int lane = threadIdx.x & 63;
    if (wave >= N_NODES/16) return;
    int m0 = wave * 16;
    int r16 = lane & 15, quad = lane >> 4;
    int row = m0 + r16;
    int g = batch[row];
    float cnt = (float)(goff[g+1] - goff[g]) * 128.f;
    cnt = fmaxf(cnt, 1.f);
    float mean = gsum[g] / cnt;
    float var = gsumsq[g] / cnt - mean*mean;
    var = fmaxf(var, 0.f);
    float rstd = rsqrtf(var + 1e-5f);

    half8_t afrag[4];
    const float* arow = hout + (size_t)row*128 + quad*8;
    #pragma unroll
    for (int kt = 0; kt < 4; ++kt) {
        int c = quad*8 + kt*32;
        const float4* v4 = (const float4*)(arow + kt*32);
        const float4* w4 = (const float4*)(lnw + c);
        const float4* b4 = (const float4*)(lnb + c);
        float4 v0 = v4[0], v1 = v4[1];
        float4 w0 = w4[0], w1 = w4[1];
        float4 bb0 = b4[0], bb1 = b4[1];
        float vv[8] = {v0.x,v0.y,v0.z,v0.w,v1.x,v1.y,v1.z,v1.w};
        float ww[8] = {w0.x,w0.y,w0.z,w0.w,w1.x,w1.y,w1.z,w1.w};
        float bz[8] = {bb0.x,bb0.y,bb0.z,bb0.w,bb1.x,bb1.y,bb1.z,bb1.w};
        #pragma unroll
        for (int j = 0; j < 8; ++j)
            afrag[kt][j] = (_Float16)((vv[j] - mean) * rstd * ww[j] + bz[j]);
    }
    #pragma unroll
    for (int nt = 0; nt < 16; ++nt) {
        floatx4 acc = {0.f, 0.f, 0.f, 0.f};
        const _Float16* brow = WT + (size_t)(nt*16 + r16)*128 + quad*8;
        #pragma unroll
        for (int kt = 0; kt < 4; ++kt) {
            half8_t bfrag = *(const half8_t*)(brow + kt*32);
            acc = __builtin_amdgcn_mfma_f32_16x16x32_f16(afrag[kt], bfrag, acc, 0, 0, 0);
        }
        int col = nt*16 + r16;
        float bv = b2[col];
        if (nt < 8) {
            #pragma unroll
            for (int r = 0; r < 4; ++r)
                xl_h[(size_t)(m0 + quad*4 + r)*128 + col] = (_Float16)(acc[r] + bv);
        } else {
            #pragma unroll
            for (int r = 0; r < 4; ++r)
                xr_h[(size_t)(m0 + quad*4 + r)*128 + (col-128)] = (_Float16)(acc[r] + bv);
        }
    }
}

// ---------------- GATv2 aggregation: one wave per node (R11 loop).
// 16 lanes per edge (8 ch/lane, one 16B half8 gather), 4 edge slots/wave.
// Max-free softmax; packed-fp16 logit math. xr read directly as fp16
// (bit-identical to prior in-register conversion).
__global__ __launch_bounds__(256) void k_gat(
    const _Float16* __restrict__ xl_h, const _Float16* __restrict__ xr_h,
    const int* __restrict__ row_ptr, const int* __restrict__ csr_src,
    const float* __restrict__ att, const float* __restrict__ bias,
    float* __restrict__ hout, float2* __restrict__ nstats) {
    int wave = (blockIdx.x * 256 + threadIdx.x) >> 6;
    int lane = threadIdx.x & 63;
    if (wave >= N_NODES) return;
    int i = wave;
    int slot = lane >> 4;        // edge slot 0..3
    int l16  = lane & 15;        // lane within edge group
    int c0   = l16 * 8;          // 8 contiguous channels per lane

    H8 atth, xrh;
    xrh.v = *(const half8_t*)(xr_h + (size_t)i*128 + c0);
    {
        const float4* a4 = (const float4*)(att + c0);
        float4 a0 = a4[0], a1 = a4[1];
        float af[8] = {a0.x,a0.y,a0.z,a0.w,a1.x,a1.y,a1.z,a1.w};
        #pragma unroll
        for (int j = 0; j < 8; ++j) atth.v[j] = (_Float16)af[j];
    }
    int p0 = row_ptr[i], p1 = row_ptr[i+1];

    float denom = 0.f;
    float acc[8];
    #pragma unroll
    for (int j = 0; j < 8; ++j) acc[j] = 0.f;

    for (int p = p0; p < p1; p += 8) {
        int e1 = p + slot, e2 = p + 4 + slot;
        int i1 = csr_src[(e1 < p1) ? e1 : (p1 - 1)];
        int i2 = csr_src[(e2 < p1) ? e2 : (p1 - 1)];
        H8 g1, g2, m1, m2;
        g1.v = *(const half8_t*)(xl_h + (size_t)i1*128 + c0);
        g2.v = *(const half8_t*)(xl_h + (size_t)i2*128 + c0);
        m1.v = g1.v + xrh.v;
        m2.v = g2.v + xrh.v;
        float pa1 = 0.f, pb1 = 0.f, pa2 = 0.f, pb2 = 0.f;
        #pragma unroll
        for (int j = 0; j < 4; ++j) {
            half2_t ab1 = __builtin_bit_cast(half2_t, m1.u[j] & 0x7FFF7FFFu);
            half2_t ab2 = __builtin_bit_cast(half2_t, m2.u[j] & 0x7FFF7FFFu);
            pa1 = __builtin_amdgcn_fdot2(m1.h2[j], atth.h2[j], pa1, false);
            pb1 = __builtin_amdgcn_fdot2(ab1,      atth.h2[j], pb1, false);
            pa2 = __builtin_amdgcn_fdot2(m2.h2[j], atth.h2[j], pa2, false);
            pb2 = __builtin_amdgcn_fdot2(ab2,      atth.h2[j], pb2, false);
        }
        float pt1 = 0.6f*pa1 + 0.4f*pb1;
        float pt2 = 0.6f*pa2 + 0.4f*pb2;
        pt1 += __shfl_xor(pt1, 1);  pt2 += __shfl_xor(pt2, 1);
        pt1 += __shfl_xor(pt1, 2);  pt2 += __shfl_xor(pt2, 2);
        float w1 = (e1 < p1) ? __expf(pt1) : 0.f;
        float w2 = (e2 < p1) ? __expf(pt2) : 0.f;
        denom += w1 + w2;
        #pragma unroll
        for (int j = 0; j < 8; ++j) {
            acc[j] = fmaf(w1, (float)g1.v[j], acc[j]);
            acc[j] = fmaf(w2, (float)g2.v[j], acc[j]);
        }
    }
    // merge the 4 edge-slot chains (lanes differing in bits 4,5)
    #pragma unroll
    for (int off = 16; off <= 32; off <<= 1) {
        denom += __shfl_xor(denom, off);
        #pragma unroll
        for (int j = 0; j < 8; ++j) acc[j] += __shfl_xor(acc[j], off);
    }
    float inv = 1.f / (denom + 1e-16f);
    float v[8];
    float s1 = 0.f, s2 = 0.f;
    #pragma unroll
    for (int j = 0; j < 8; ++j) {
        v[j] = acc[j] * inv + bias[c0 + j];
        s1 += v[j];
        s2 = fmaf(v[j], v[j], s2);
    }
    if (slot == 0) {
        float4* o4 = (float4*)(hout + (size_t)i*128 + c0);
        o4[0] = make_float4(v[0], v[1], v[2], v[3]);
        o4[1] = make_float4(v[4], v[5], v[6], v[7]);
    }
    #pragma unroll
    for (int off = 1; off < 16; off <<= 1) {
        s1 += __shfl_xor(s1, off);
        s2 += __shfl_xor(s2, off);
    }
    if (lane == 0) nstats[i] = make_float2(s1, s2);
}

// ---------------- per-graph reduction of node stats (plain stores) ----------
__global__ __launch_bounds__(256) void k_graph_red(
    const float2* __restrict__ nstats, const int* __restrict__ goff,
    float* __restrict__ gsum, float* __restrict__ gsumsq) {
    __shared__ float l1[256], l2[256];
    int g = blockIdx.x;
    int tid = threadIdx.x;
    int a = goff[g], b = goff[g+1];
    float s1 = 0.f, s2 = 0.f;
    for (int i = a + tid; i < b; i += 256) {
        float2 v = nstats[i];
        s1 += v.x; s2 += v.y;
    }
    l1[tid] = s1; l2[tid] = s2; __syncthreads();
    for (int off = 128; off > 0; off >>= 1) {
        if (tid < off) { l1[tid] += l1[tid+off]; l2[tid] += l2[tid+off]; }
        __syncthreads();
    }
    if (tid == 0) { gsum[g] = l1[0]; gsumsq[g] = l2[0]; }
}

// ---------------- final graph layernorm (fp16 out, feeds k_pairs only) -------
__global__ void k_ln(const float* __restrict__ hout, const int* __restrict__ batch,
                     const int* __restrict__ goff, const float* __restrict__ gsum,
                     const float* __restrict__ gsumsq, const float* __restrict__ w,
                     const float* __restrict__ b, _Float16* __restrict__ hb) {
    int idx = blockIdx.x*256 + threadIdx.x;
    if (idx >= N_NODES*128) return;
    int i = idx >> 7, c = idx & 127;
    int g = batch[i];
    float cnt = (float)(goff[g+1] - goff[g]) * 128.f;
    cnt = fmaxf(cnt, 1.f);
    float mean = gsum[g] / cnt;
    float var = gsumsq[g] / cnt - mean*mean;
    var = fmaxf(var, 0.f);
    float rstd = rsqrtf(var + 1e-5f);
    float v = (hout[idx] - mean) * rstd * w[c] + b[c];
    hb[idx] = (_Float16)v;
}

// ---------------- pair scoring: 16 lanes/pair, SINGLE gathered array,
// link_W folded into per-lane fp16 registers ----------
__global__ __launch_bounds__(256) void k_pairs(
    const _Float16* __restrict__ hb, const int* __restrict__ pi,
    const float* __restrict__ lW, const float* __restrict__ lb,
    float* __restrict__ out) {
    int grp = (blockIdx.x*256 + threadIdx.x) >> 4;
    int q = threadIdx.x & 15;
    if (grp >= N_PAIRS) return;
    H8 w;
    #pragma unroll
    for (int j = 0; j < 8; ++j) w.v[j] = (_Float16)lW[q*8 + j];
    int p0 = pi[grp], p1 = pi[N_PAIRS + grp];
    const half8_t* B = (const half8_t*)hb;
    H8 a, b, prod;
    a.v = B[(size_t)p0*16 + q];
    b.v = B[(size_t)p1*16 + q];
    prod.v = a.v * b.v;
    float part = 0.f;
    #pragma unroll
    for (int j = 0; j < 4; ++j)
        part = __builtin_amdgcn_fdot2(prod.h2[j], w.h2[j], part, false);
    part += __shfl_xor(part, 1);
    part += __shfl_xor(part, 2);
    part += __shfl_xor(part, 4);
    part += __shfl_xor(part, 8);
    if (q == 0) out[grp] = 1.f / (1.f + __expf(-(part + lb[0])));
}

extern "C" void kernel_launch(void* const* d_in, const int* in_sizes, int n_in,
                              void* d_out, int out_size, void* d_ws, size_t ws_size,
                              hipStream_t stream) {
    const float* x     = (const float*)d_in[0];
    const float* t     = (const float*)d_in[1];
    const int*   ei    = (const int*)  d_in[2];
    const int*   pi    = (const int*)  d_in[3];
    const int*   batch = (const int*)  d_in[4];
    const float* tW    = (const float*)d_in[5];
    const float* tb    = (const float*)d_in[6];
    const float* W0l   = (const float*)d_in[7];
    const float* b0l   = (const float*)d_in[8];
    const float* W0r   = (const float*)d_in[9];
    const float* b0r   = (const float*)d_in[10];
    const float* att0  = (const float*)d_in[11];
    const float* bias0 = (const float*)d_in[12];
    const float* Wl    = (const float*)d_in[13];
    const float* bl    = (const float*)d_in[14];
    const float* Wr    = (const float*)d_in[15];
    const float* br    = (const float*)d_in[16];
    const float* att   = (const float*)d_in[17];
    const float* bias  = (const float*)d_in[18];
    const float* lnw   = (const float*)d_in[19];
    const float* lnb   = (const float*)d_in[20];
    const float* lW    = (const float*)d_in[21];
    const float* lb    = (const float*)d_in[22];
    float* out = (float*)d_out;

    char* ws = (char*)d_ws;
    size_t off = 0;
    auto walloc = [&](size_t bytes) -> void* {
        void* p = ws + off;
        off += (bytes + 255) & ~(size_t)255;
        return p;
    };
    _Float16*  h0h     = (_Float16*) walloc((size_t)N_NODES*384*2);
    float*     hout    = (float*)    walloc((size_t)N_NODES*128*4);
    _Float16*  xl_h    = (_Float16*) walloc((size_t)N_NODES*128*2);
    _Float16*  xr_h    = (_Float16*) walloc((size_t)N_NODES*128*2);
    _Float16*  hb      = (_Float16*) walloc((size_t)N_NODES*128*2);
    int*       row_ptr = (int*)      walloc((size_t)(N_NODES+1)*4);
    int*       csr_src = (int*)      walloc((size_t)E_TOT*4);
    unsigned int* stage = (unsigned int*)walloc((size_t)E_TOT*4);
    int*       bcnt    = (int*)      walloc(NB2*4);
    int*       bbase   = (int*)      walloc((NB2+1)*4);
    int*       bcursor = (int*)      walloc(NB2*4);
    int*       goff    = (int*)      walloc(64*4);
    float2*    nstats  = (float2*)   walloc((size_t)N_NODES*8);
    float*     stats   = (float*)    walloc(2*64*4);              // [sum|sumsq][64]
    _Float16*  WT0     = (_Float16*) walloc(256*384*2);
    _Float16*  WT123   = (_Float16*) walloc(3*256*128*2);
    float*     b2      = (float*)    walloc(4*256*4);

    hipMemsetAsync(bcnt, 0, NB2*4, stream);

    k_time_embed<<<N_NODES, 256, 0, stream>>>(x, t, tW, tb, h0h);
    k_cvt_all<<<(256*384 + 3*256*128 + 255)/256, 256, 0, stream>>>(
        W0l, W0r, b0l, b0r, Wl, Wr, bl, br, WT0, WT123, b2);
    k_goff<<<SCAN_NB, 256, 0, stream>>>(batch, goff);
    k_bhist<<<SCAT_BLOCKS, 256, 0, stream>>>(ei, bcnt);
    k_bscan<<<1, 256, 0, stream>>>(bcnt, bbase, bcursor);
    k_scat1<<<SCAT_BLOCKS, 256, 0, stream>>>(ei, bcursor, stage);
    k_scat2<<<NB2, 256, 0, stream>>>(stage, bbase, row_ptr, csr_src);

    float* gsum   = stats;
    float* gsumsq = stats + 64;
    const int GEMM_BLOCKS = (N_NODES/16 + 3) / 4;   // 4 waves/block, 16 rows/wave
    for (int L = 0; L < 4; ++L) {
        if (L == 0)
            k_gemm_mfma<384><<<GEMM_BLOCKS, 256, 0, stream>>>(h0h, WT0, b2, xl_h, xr_h);
        else
            k_gemm_ln_mfma<<<GEMM_BLOCKS, 256, 0, stream>>>(
                hout, batch, goff, gsum, gsumsq, lnw + (L-1)*128, lnb + (L-1)*128,
                WT123 + (size_t)(L-1)*256*128, b2 + L*256, xl_h, xr_h);
        const float* attL  = (L == 0) ? att0  : att  + (size_t)(L-1)*128;
        const float* biasL = (L == 0) ? bias0 : bias + (size_t)(L-1)*128;
        k_gat<<<N_NODES/4, 256, 0, stream>>>(xl_h, xr_h, row_ptr, csr_src, attL, biasL,
                                             hout, nstats);
        k_graph_red<<<N_GRAPHS, 256, 0, stream>>>(nstats, goff, gsum, gsumsq);
    }
    k_ln<<<(N_NODES*128+255)/256, 256, 0, stream>>>(hout, batch, goff, gsum, gsumsq,
                                                    lnw + 3*128, lnb + 3*128, hb);
    k_pairs<<<((size_t)N_PAIRS*16 + 255)/256, 256, 0, stream>>>(hb, pi, lW, lb, out);
}